// Round 2
// baseline (596.417 us; speedup 1.0000x reference)
//
#include <hip/hip_runtime.h>
#include <hip/hip_fp16.h>

#define N    8192
#define FIN  256
#define FOUT 128
#define BN   64

typedef _Float16 half8 __attribute__((ext_vector_type(8)));
typedef _Float16 half4v __attribute__((ext_vector_type(4)));
typedef float floatx4 __attribute__((ext_vector_type(4)));

// v_exp_f32 computes 2^x directly; __exp2f is not declared in these headers.
__device__ __forceinline__ float exp2_fast(float x) { return __builtin_amdgcn_exp2f(x); }

// ---------------------------------------------------------------------------
// W-prep: frag-major fp16 W for coalesced MFMA B-loads.
// ---------------------------------------------------------------------------
__global__ __launch_bounds__(256)
void wprep_kernel(const float* __restrict__ W0,
                  const float* __restrict__ W1,
                  const float* __restrict__ W2,
                  _Float16* __restrict__ Wf)
{
    int idx  = blockIdx.x * 256 + threadIdx.x;   // 0..12287
    int lane = idx & 63;
    int frag = idx >> 6;
    int w    = frag >> 6;
    int f    = frag & 63;
    int nt   = f >> 3, kc = f & 7;
    int quad = lane >> 4, lo16 = lane & 15;
    const float* Wp = w == 0 ? W0 : (w == 1 ? W1 : W2);
    half8 v;
#pragma unroll
    for (int jj = 0; jj < 8; jj++)
        v[jj] = (_Float16)Wp[(size_t)(kc * 32 + quad * 8 + jj) * FOUT + nt * 16 + lo16];
    *(half8*)&Wf[(size_t)idx * 8] = v;
}

// ---------------------------------------------------------------------------
// H = fp16(log2e * inp@W)  (Q side, pre-scaled so softmax runs in exp2 domain),
// H2 = fp16(inp@W2), H3T = fp16((inp@W3)^T). Barrier-free.
// ---------------------------------------------------------------------------
__global__ __launch_bounds__(256, 2)
void gemm3_kernel(const float* __restrict__ inp,
                  const _Float16* __restrict__ Wf,
                  _Float16* __restrict__ H,
                  _Float16* __restrict__ H2,
                  _Float16* __restrict__ H3T)
{
    const int which = blockIdx.z;
    const int c0    = blockIdx.y * 64;
    const _Float16* Wfw = Wf + (size_t)which * 64 * 64 * 8;
    const int r0 = blockIdx.x * 64;
    const int tid  = threadIdx.x;
    const int wave = tid >> 6;
    const int lane = tid & 63;
    const int lo16 = lane & 15;
    const int quad = lane >> 4;
    const int r = r0 + wave * 16 + lo16;

    half8 a[8];
#pragma unroll
    for (int kc = 0; kc < 8; kc++) {
        const float* p = &inp[(size_t)r * FIN + kc * 32 + quad * 8];
        float4 v0 = *(const float4*)p;
        float4 v1 = *(const float4*)(p + 4);
        a[kc][0] = (_Float16)v0.x; a[kc][1] = (_Float16)v0.y;
        a[kc][2] = (_Float16)v0.z; a[kc][3] = (_Float16)v0.w;
        a[kc][4] = (_Float16)v1.x; a[kc][5] = (_Float16)v1.y;
        a[kc][6] = (_Float16)v1.z; a[kc][7] = (_Float16)v1.w;
    }

    floatx4 acc[4];
#pragma unroll
    for (int i = 0; i < 4; i++) acc[i] = (floatx4){0.f, 0.f, 0.f, 0.f};

#pragma unroll
    for (int kc = 0; kc < 8; kc++)
#pragma unroll
        for (int nt = 0; nt < 4; nt++) {
            int ntg = (c0 >> 4) + nt;
            half8 b = *(const half8*)&Wfw[(((size_t)ntg * 8 + kc) * 64 + lane) * 8];
            acc[nt] = __builtin_amdgcn_mfma_f32_16x16x32_f16(a[kc], b, acc[nt], 0, 0, 0);
        }

    const int arow = wave * 16 + quad * 4;
    if (which < 2) {
        _Float16* outp = which == 0 ? H : H2;
        const float scale = which == 0 ? 1.44269504f : 1.0f;   // log2(e) folded into Q
#pragma unroll
        for (int nt = 0; nt < 4; nt++)
#pragma unroll
            for (int rr = 0; rr < 4; rr++)
                outp[(size_t)(r0 + arow + rr) * FOUT + c0 + nt * 16 + lo16] =
                    (_Float16)(acc[nt][rr] * scale);
    } else {
#pragma unroll
        for (int nt = 0; nt < 4; nt++) {
            half4v v;
#pragma unroll
            for (int rr = 0; rr < 4; rr++) v[rr] = (_Float16)acc[nt][rr];
            *(half4v*)&H3T[(size_t)(c0 + nt * 16 + lo16) * N + r0 + arow] = v;
        }
    }
}

// ---------------------------------------------------------------------------
// Fused repack: blocks [0,512) build Kf (sigma j-permutation baked in),
// blocks [512,1024) build Vf.
// ---------------------------------------------------------------------------
__global__ __launch_bounds__(256)
void repackKV_kernel(const _Float16* __restrict__ H2,
                     const _Float16* __restrict__ H3T,
                     _Float16* __restrict__ Kf,
                     _Float16* __restrict__ Vf)
{
    if (blockIdx.x < 512) {
        int idx  = blockIdx.x * 256 + threadIdx.x;
        int lane = idx & 63;
        int frag = idx >> 6;
        int jb = frag >> 4, f = frag & 15;
        int c = f >> 3, ntj = (f >> 2) & 1, kc = f & 3;
        int quad = lane >> 4, lo16 = lane & 15;
        int srcrow = jb * 64 + c * 32 + (lo16 >> 2) * 8 + ntj * 4 + (lo16 & 3);
        half8 v = *(const half8*)&H2[(size_t)srcrow * FOUT + kc * 32 + quad * 8];
        *(half8*)&Kf[(size_t)idx * 8] = v;
    } else {
        int idx  = (blockIdx.x - 512) * 256 + threadIdx.x;
        int lane = idx & 63;
        int frag = idx >> 6;
        int jb = frag >> 4, f = frag & 15, nt = f >> 1, kc = f & 1;
        int quad = lane >> 4, lo16 = lane & 15;
        half8 v = *(const half8*)&H3T[(size_t)(nt * 16 + lo16) * N + jb * 64 + kc * 32 + quad * 8];
        *(half8*)&Vf[(size_t)idx * 8] = v;
    }
}

// ---------------------------------------------------------------------------
// adj bit-pack: streaming 268 MB read -> adjb[N][N/64] uint64.
// Bit l of adjb[i][w] = (adj[i][w*64+l] != 0). One wave per (row, 256-col)
// task: 4x coalesced 256B loads, 4 ballots, 32B write.
// ---------------------------------------------------------------------------
__global__ __launch_bounds__(256)
void adjpack_kernel(const int* __restrict__ adj,
                    unsigned long long* __restrict__ adjb)
{
    const int gw   = (blockIdx.x * 256 + threadIdx.x) >> 6;   // global wave id
    const int lane = threadIdx.x & 63;
    const int NW   = 2048 * 4;                                // total waves
    for (int t = gw; t < N * 32; t += NW) {
        int row = t >> 5, c4 = t & 31;
        const int* p = adj + (size_t)row * N + c4 * 256 + lane;
        int a0 = p[0], a1 = p[64], a2 = p[128], a3 = p[192];
        unsigned long long b0 = __ballot(a0 != 0);
        unsigned long long b1 = __ballot(a1 != 0);
        unsigned long long b2 = __ballot(a2 != 0);
        unsigned long long b3 = __ballot(a3 != 0);
        unsigned long long v = lane == 0 ? b0 : (lane == 1 ? b1 : (lane == 2 ? b2 : b3));
        if (lane < 4) adjb[(size_t)row * (N / 64) + c4 * 4 + lane] = v;
    }
}

// ---------------------------------------------------------------------------
// Flash attention, R11: no-LDS (K/V frags read straight from L2-resident
// Kf/Vf via js->XCD affinity), barrier-free, bitpacked adj masks, exp2-domain
// softmax (log2e pre-folded into Hq), threshold-deferred O-rescale.
// ---------------------------------------------------------------------------
template<int JS>
__global__ __launch_bounds__(256, 2)
void attn_kernel(const _Float16* __restrict__ Hq,   // [N][128], pre-scaled by log2e
                 const _Float16* __restrict__ Kf,   // permuted frag-major
                 const _Float16* __restrict__ Vf,   // frag-major
                 const unsigned long long* __restrict__ adjb, // [N][N/64]
                 float* __restrict__ OpartT,        // [JS][FOUT][N]
                 float* __restrict__ mpart,         // [JS][N]  (log2 domain)
                 float* __restrict__ lpart)         // [JS][N]
{
    const int tid  = threadIdx.x;
    const int wave = tid >> 6;
    const int lane = tid & 63;
    const int lo16 = lane & 15;
    const int quad = lane >> 4;
    const int bid  = blockIdx.x;
    const int js   = bid & (JS - 1);      // XCD affinity
    const int ib   = bid / JS;
    const int iw   = ib * 128 + wave * 32;
    const int jbeg = js * (N / JS);
    const int NIT  = (N / JS) / BN;

    // Q as B-operand fragments for 2 i-subtiles
    half8 q[2][4];
#pragma unroll
    for (int isub = 0; isub < 2; isub++)
#pragma unroll
        for (int kc = 0; kc < 4; kc++)
            q[isub][kc] = *(const half8*)&Hq[(size_t)(iw + isub * 16 + lo16) * FOUT + kc * 32 + quad * 8];

    floatx4 O[8][2];
#pragma unroll
    for (int nt = 0; nt < 8; nt++)
#pragma unroll
        for (int s = 0; s < 2; s++) O[nt][s] = (floatx4){0.f, 0.f, 0.f, 0.f};
    float m_s[2] = {-1e12f, -1e12f}, l_s[2] = {0.f, 0.f};

    // per-lane mask row pointers: row i = iw + s*16 + lo16, window = j/64
    const unsigned long long* ar0 = adjb + (size_t)(iw + lo16) * (N / 64) + (jbeg >> 6);
    const unsigned long long* ar1 = ar0 + (size_t)16 * (N / 64);

    for (int it = 0; it < NIT; it++) {
        const _Float16* kb = Kf + (size_t)((jbeg >> 6) + it) * 8192;
        const _Float16* vb = Vf + (size_t)((jbeg >> 6) + it) * 8192;
        unsigned long long mw[2] = { ar0[it], ar1[it] };

        // ---- S^T = K Q^T : j = c*32 + 8*quad + 4*ntj + r, i = s*16+lo16 ----
        floatx4 S[2][2][2];   // [c][ntj][isub]
#pragma unroll
        for (int c = 0; c < 2; c++)
#pragma unroll
            for (int ntj = 0; ntj < 2; ntj++) {
                S[c][ntj][0] = (floatx4){0.f, 0.f, 0.f, 0.f};
                S[c][ntj][1] = (floatx4){0.f, 0.f, 0.f, 0.f};
#pragma unroll
                for (int kc = 0; kc < 4; kc++) {
                    half8 kf = *(const half8*)&kb[(((c * 2 + ntj) * 4 + kc) * 64 + lane) * 8];
                    S[c][ntj][0] = __builtin_amdgcn_mfma_f32_16x16x32_f16(kf, q[0][kc], S[c][ntj][0], 0, 0, 0);
                    S[c][ntj][1] = __builtin_amdgcn_mfma_f32_16x16x32_f16(kf, q[1][kc], S[c][ntj][1], 0, 0, 0);
                }
            }

        // ---- online softmax (exp2 domain), in-place lrelu, deferred rescale
        half8 pb[2][2];       // [isub][c], element jj = 4*ntj + r
#pragma unroll
        for (int s = 0; s < 2; s++) {
            float mx = -1e12f;
#pragma unroll
            for (int c = 0; c < 2; c++)
#pragma unroll
                for (int ntj = 0; ntj < 2; ntj++)
#pragma unroll
                    for (int r = 0; r < 4; r++) {
                        float e = S[c][ntj][s][r];
                        e = fmaxf(e, 0.2f * e);          // lrelu (scale-commutes)
                        S[c][ntj][s][r] = e;             // store post-lrelu
                        mx = fmaxf(mx, e);
                    }
            mx = fmaxf(mx, __shfl_xor(mx, 16));
            mx = fmaxf(mx, __shfl_xor(mx, 32));
            // deferred rescale: only when max grew past ~4 nats (5.75 in log2)
            if (__any(mx > m_s[s] + 5.75f)) {
                float mn = fmaxf(m_s[s], mx);
                float al = exp2_fast(m_s[s] - mn);
                m_s[s] = mn;
                l_s[s] *= al;
#pragma unroll
                for (int nt = 0; nt < 8; nt++)
#pragma unroll
                    for (int r = 0; r < 4; r++)
                        O[nt][s][r] *= al;
            }

            unsigned long long mq = mw[s] >> (quad * 8);
            unsigned mh[2] = { (unsigned)mq, (unsigned)(mq >> 32) };
            float sum = 0.f;
#pragma unroll
            for (int c = 0; c < 2; c++)
#pragma unroll
                for (int ntj = 0; ntj < 2; ntj++)
#pragma unroll
                    for (int r = 0; r < 4; r++) {
                        float e = S[c][ntj][s][r] - m_s[s];
                        bool bit = (mh[c] >> (ntj * 4 + r)) & 1u;
                        float p = bit ? exp2_fast(e) : 0.f;
                        sum += p;
                        pb[s][c][ntj * 4 + r] = (_Float16)p;
                    }
            sum += __shfl_xor(sum, 16);
            sum += __shfl_xor(sum, 32);
            l_s[s] += sum;
        }

        // ---- O^T += V^T P^T ----
#pragma unroll
        for (int c = 0; c < 2; c++)
#pragma unroll
            for (int nt = 0; nt < 8; nt++) {
                half8 vf = *(const half8*)&vb[((nt * 2 + c) * 64 + lane) * 8];
                O[nt][0] = __builtin_amdgcn_mfma_f32_16x16x32_f16(vf, pb[0][c], O[nt][0], 0, 0, 0);
                O[nt][1] = __builtin_amdgcn_mfma_f32_16x16x32_f16(vf, pb[1][c], O[nt][1], 0, 0, 0);
            }
    }

    // epilogue: O^T[f][i] -> OpartT[js][f][i] (unnormalized) + (m,l)
#pragma unroll
    for (int nt = 0; nt < 8; nt++)
#pragma unroll
        for (int s = 0; s < 2; s++)
#pragma unroll
            for (int r = 0; r < 4; r++) {
                int f = nt * 16 + quad * 4 + r;
                int i = iw + s * 16 + lo16;
                OpartT[((size_t)js * FOUT + f) * N + i] = O[nt][s][r];
            }
    if (quad == 0) {
#pragma unroll
        for (int s = 0; s < 2; s++) {
            mpart[js * N + iw + s * 16 + lo16] = m_s[s];
            lpart[js * N + iw + s * 16 + lo16] = l_s[s];
        }
    }
}

// ---------------------------------------------------------------------------
// Combine: f-major partials -> normalize -> ELU -> out[i][f].
// m is in log2 domain -> exp2 for the cross-partial weights.
// ---------------------------------------------------------------------------
template<int JS>
__global__ __launch_bounds__(256)
void combine_kernel(const float* __restrict__ OpartT,
                    const float* __restrict__ mpart,
                    const float* __restrict__ lpart,
                    float* __restrict__ out)
{
    int idx = blockIdx.x * 256 + threadIdx.x;   // 128 f x 2048 i-groups
    int f  = idx >> 11;
    int i4 = (idx & 2047) << 2;

    float4 M = {-3e38f, -3e38f, -3e38f, -3e38f};
    float4 m[JS];
#pragma unroll
    for (int s = 0; s < JS; s++) {
        m[s] = *(const float4*)&mpart[s * N + i4];
        M.x = fmaxf(M.x, m[s].x); M.y = fmaxf(M.y, m[s].y);
        M.z = fmaxf(M.z, m[s].z); M.w = fmaxf(M.w, m[s].w);
    }
    float4 L = {0.f, 0.f, 0.f, 0.f};
    float4 w[JS];
#pragma unroll
    for (int s = 0; s < JS; s++) {
        float4 l = *(const float4*)&lpart[s * N + i4];
        w[s].x = exp2_fast(m[s].x - M.x); w[s].y = exp2_fast(m[s].y - M.y);
        w[s].z = exp2_fast(m[s].z - M.z); w[s].w = exp2_fast(m[s].w - M.w);
        L.x += l.x * w[s].x; L.y += l.y * w[s].y;
        L.z += l.z * w[s].z; L.w += l.w * w[s].w;
    }
    float4 o = {0.f, 0.f, 0.f, 0.f};
#pragma unroll
    for (int s = 0; s < JS; s++) {
        float4 v = *(const float4*)&OpartT[((size_t)s * FOUT + f) * N + i4];
        o.x += w[s].x * v.x; o.y += w[s].y * v.y;
        o.z += w[s].z * v.z; o.w += w[s].w * v.w;
    }
    float r0 = o.x / L.x, r1 = o.y / L.y, r2 = o.z / L.z, r3 = o.w / L.w;
    out[(size_t)(i4 + 0) * FOUT + f] = r0 > 0.f ? r0 : __expf(r0) - 1.f;
    out[(size_t)(i4 + 1) * FOUT + f] = r1 > 0.f ? r1 : __expf(r1) - 1.f;
    out[(size_t)(i4 + 2) * FOUT + f] = r2 > 0.f ? r2 : __expf(r2) - 1.f;
    out[(size_t)(i4 + 3) * FOUT + f] = r3 > 0.f ? r3 : __expf(r3) - 1.f;
}

// ---------------------------------------------------------------------------
extern "C" void kernel_launch(void* const* d_in, const int* in_sizes, int n_in,
                              void* d_out, int out_size, void* d_ws, size_t ws_size,
                              hipStream_t stream) {
    const float* inp = (const float*)d_in[0];
    const int*   adj = (const int*)d_in[1];
    const float* W0  = (const float*)d_in[2];
    const float* W1  = (const float*)d_in[3];
    const float* W2  = (const float*)d_in[4];
    float* out = (float*)d_out;

    constexpr int JS = 8;
    char* ws = (char*)d_ws;
    _Float16* H    = (_Float16*)(ws);                          // 2 MB
    _Float16* H2   = (_Float16*)(ws + (2u << 20));             // 2 MB
    _Float16* H3T  = (_Float16*)(ws + (4u << 20));             // 2 MB
    _Float16* Wf   = (_Float16*)(ws + (6u << 20));             // 192 KB
    _Float16* Kf   = (_Float16*)(ws + (7u << 20));             // 2 MB
    _Float16* Vf   = (_Float16*)(ws + (9u << 20));             // 2 MB
    float* OpartT  = (float*)(ws + (11u << 20));               // 32 MB
    float* mpart   = (float*)(ws + (43u << 20));               // 256 KB
    float* lpart   = (float*)(ws + (43u << 20) + (size_t)JS * N * sizeof(float));
    unsigned long long* adjb = (unsigned long long*)(ws + (44u << 20)); // 8 MB

    wprep_kernel<<<48, 256, 0, stream>>>(W0, W1, W2, Wf);
    gemm3_kernel<<<dim3(N / 64, 2, 3), 256, 0, stream>>>(inp, Wf, H, H2, H3T);
    repackKV_kernel<<<1024, 256, 0, stream>>>(H2, H3T, Kf, Vf);
    adjpack_kernel<<<2048, 256, 0, stream>>>(adj, adjb);
    attn_kernel<JS><<<(N / 128) * JS, 256, 0, stream>>>(H, Kf, Vf, adjb, OpartT, mpart, lpart);
    combine_kernel<JS><<<(FOUT * (N / 4)) / 256, 256, 0, stream>>>(OpartT, mpart, lpart, out);
}

// Round 3
// 437.280 us; speedup vs baseline: 1.3639x; 1.3639x over previous
//
#include <hip/hip_runtime.h>
#include <hip/hip_fp16.h>

#define N    8192
#define FIN  256
#define FOUT 128
#define BN   64

typedef _Float16 half8 __attribute__((ext_vector_type(8)));
typedef _Float16 half4v __attribute__((ext_vector_type(4)));
typedef float floatx4 __attribute__((ext_vector_type(4)));

// v_exp_f32 computes 2^x directly; __exp2f is not declared in these headers.
__device__ __forceinline__ float exp2_fast(float x) { return __builtin_amdgcn_exp2f(x); }

// Direct global->LDS DMA, 16 B per lane. LDS dest is wave-uniform base +
// lane*16; our staging layout is linear in tid so this matches exactly.
__device__ __forceinline__ void gload_lds16(const void* g, void* l) {
    __builtin_amdgcn_global_load_lds(
        (const __attribute__((address_space(1))) void*)g,
        (__attribute__((address_space(3))) void*)l, 16, 0, 0);
}

// ---------------------------------------------------------------------------
// Fused prep: blocks [0,48) build frag-major fp16 W; blocks [48,2096) bit-pack
// adj (268 MB stream) into adjb[N][N/64] uint64.
// ---------------------------------------------------------------------------
__global__ __launch_bounds__(256)
void prep_kernel(const float* __restrict__ W0,
                 const float* __restrict__ W1,
                 const float* __restrict__ W2,
                 _Float16* __restrict__ Wf,
                 const int* __restrict__ adj,
                 unsigned long long* __restrict__ adjb)
{
    if (blockIdx.x < 48) {
        int idx  = blockIdx.x * 256 + threadIdx.x;   // 0..12287
        int lane = idx & 63;
        int frag = idx >> 6;
        int w    = frag >> 6;
        int f    = frag & 63;
        int nt   = f >> 3, kc = f & 7;
        int quad = lane >> 4, lo16 = lane & 15;
        const float* Wp = w == 0 ? W0 : (w == 1 ? W1 : W2);
        half8 v;
#pragma unroll
        for (int jj = 0; jj < 8; jj++)
            v[jj] = (_Float16)Wp[(size_t)(kc * 32 + quad * 8 + jj) * FOUT + nt * 16 + lo16];
        *(half8*)&Wf[(size_t)idx * 8] = v;
    } else {
        const int gw   = ((blockIdx.x - 48) * 256 + threadIdx.x) >> 6;  // global wave id
        const int lane = threadIdx.x & 63;
        const int NW   = 2048 * 4;                                      // total waves
        for (int t = gw; t < N * 32; t += NW) {
            int row = t >> 5, c4 = t & 31;
            const int* p = adj + (size_t)row * N + c4 * 256 + lane;
            int a0 = p[0], a1 = p[64], a2 = p[128], a3 = p[192];
            unsigned long long b0 = __ballot(a0 != 0);
            unsigned long long b1 = __ballot(a1 != 0);
            unsigned long long b2 = __ballot(a2 != 0);
            unsigned long long b3 = __ballot(a3 != 0);
            unsigned long long v = lane == 0 ? b0 : (lane == 1 ? b1 : (lane == 2 ? b2 : b3));
            if (lane < 4) adjb[(size_t)row * (N / 64) + c4 * 4 + lane] = v;
        }
    }
}

// ---------------------------------------------------------------------------
// H = fp16(log2e * inp@W)  (Q side, pre-scaled so softmax runs in exp2 domain),
// H2 = fp16(inp@W2), H3T = fp16((inp@W3)^T). Barrier-free.
// ---------------------------------------------------------------------------
__global__ __launch_bounds__(256, 2)
void gemm3_kernel(const float* __restrict__ inp,
                  const _Float16* __restrict__ Wf,
                  _Float16* __restrict__ H,
                  _Float16* __restrict__ H2,
                  _Float16* __restrict__ H3T)
{
    const int which = blockIdx.z;
    const int c0    = blockIdx.y * 64;
    const _Float16* Wfw = Wf + (size_t)which * 64 * 64 * 8;
    const int r0 = blockIdx.x * 64;
    const int tid  = threadIdx.x;
    const int wave = tid >> 6;
    const int lane = tid & 63;
    const int lo16 = lane & 15;
    const int quad = lane >> 4;
    const int r = r0 + wave * 16 + lo16;

    half8 a[8];
#pragma unroll
    for (int kc = 0; kc < 8; kc++) {
        const float* p = &inp[(size_t)r * FIN + kc * 32 + quad * 8];
        float4 v0 = *(const float4*)p;
        float4 v1 = *(const float4*)(p + 4);
        a[kc][0] = (_Float16)v0.x; a[kc][1] = (_Float16)v0.y;
        a[kc][2] = (_Float16)v0.z; a[kc][3] = (_Float16)v0.w;
        a[kc][4] = (_Float16)v1.x; a[kc][5] = (_Float16)v1.y;
        a[kc][6] = (_Float16)v1.z; a[kc][7] = (_Float16)v1.w;
    }

    floatx4 acc[4];
#pragma unroll
    for (int i = 0; i < 4; i++) acc[i] = (floatx4){0.f, 0.f, 0.f, 0.f};

#pragma unroll
    for (int kc = 0; kc < 8; kc++)
#pragma unroll
        for (int nt = 0; nt < 4; nt++) {
            int ntg = (c0 >> 4) + nt;
            half8 b = *(const half8*)&Wfw[(((size_t)ntg * 8 + kc) * 64 + lane) * 8];
            acc[nt] = __builtin_amdgcn_mfma_f32_16x16x32_f16(a[kc], b, acc[nt], 0, 0, 0);
        }

    const int arow = wave * 16 + quad * 4;
    if (which < 2) {
        _Float16* outp = which == 0 ? H : H2;
        const float scale = which == 0 ? 1.44269504f : 1.0f;   // log2(e) folded into Q
#pragma unroll
        for (int nt = 0; nt < 4; nt++)
#pragma unroll
            for (int rr = 0; rr < 4; rr++)
                outp[(size_t)(r0 + arow + rr) * FOUT + c0 + nt * 16 + lo16] =
                    (_Float16)(acc[nt][rr] * scale);
    } else {
#pragma unroll
        for (int nt = 0; nt < 4; nt++) {
            half4v v;
#pragma unroll
            for (int rr = 0; rr < 4; rr++) v[rr] = (_Float16)acc[nt][rr];
            *(half4v*)&H3T[(size_t)(c0 + nt * 16 + lo16) * N + r0 + arow] = v;
        }
    }
}

// ---------------------------------------------------------------------------
// Fused repack: blocks [0,512) build Kf (sigma j-permutation baked in),
// blocks [512,1024) build Vf.
// ---------------------------------------------------------------------------
__global__ __launch_bounds__(256)
void repackKV_kernel(const _Float16* __restrict__ H2,
                     const _Float16* __restrict__ H3T,
                     _Float16* __restrict__ Kf,
                     _Float16* __restrict__ Vf)
{
    if (blockIdx.x < 512) {
        int idx  = blockIdx.x * 256 + threadIdx.x;
        int lane = idx & 63;
        int frag = idx >> 6;
        int jb = frag >> 4, f = frag & 15;
        int c = f >> 3, ntj = (f >> 2) & 1, kc = f & 3;
        int quad = lane >> 4, lo16 = lane & 15;
        int srcrow = jb * 64 + c * 32 + (lo16 >> 2) * 8 + ntj * 4 + (lo16 & 3);
        half8 v = *(const half8*)&H2[(size_t)srcrow * FOUT + kc * 32 + quad * 8];
        *(half8*)&Kf[(size_t)idx * 8] = v;
    } else {
        int idx  = (blockIdx.x - 512) * 256 + threadIdx.x;
        int lane = idx & 63;
        int frag = idx >> 6;
        int jb = frag >> 4, f = frag & 15, nt = f >> 1, kc = f & 1;
        int quad = lane >> 4, lo16 = lane & 15;
        half8 v = *(const half8*)&H3T[(size_t)(nt * 16 + lo16) * N + jb * 64 + kc * 32 + quad * 8];
        *(half8*)&Vf[(size_t)idx * 8] = v;
    }
}

// ---------------------------------------------------------------------------
// Flash attention, R12: double-buffered LDS KV staging via global_load_lds
// (width 16, linear layout), 1 barrier/iter; bitpacked adj masks; exp2-domain
// softmax (log2e pre-folded into Hq); threshold-deferred O-rescale.
// ---------------------------------------------------------------------------
template<int JS>
__global__ __launch_bounds__(256, 2)
void attn_kernel(const _Float16* __restrict__ Hq,   // [N][128], pre-scaled by log2e
                 const _Float16* __restrict__ Kf,   // permuted frag-major
                 const _Float16* __restrict__ Vf,   // frag-major
                 const unsigned long long* __restrict__ adjb, // [N][N/64]
                 float* __restrict__ OpartT,        // [JS][FOUT][N]
                 float* __restrict__ mpart,         // [JS][N]  (log2 domain)
                 float* __restrict__ lpart)         // [JS][N]
{
    __shared__ __align__(16) _Float16 KV[2][16384];   // [buf][16 K frags | 16 V frags]

    const int tid  = threadIdx.x;
    const int wave = tid >> 6;
    const int lane = tid & 63;
    const int lo16 = lane & 15;
    const int quad = lane >> 4;
    const int bid  = blockIdx.x;
    const int js   = bid & (JS - 1);      // XCD affinity
    const int ib   = bid / JS;
    const int iw   = ib * 128 + wave * 32;
    const int jbeg = js * (N / JS);
    const int NIT  = (N / JS) / BN;

    // Q as B-operand fragments for 2 i-subtiles
    half8 q[2][4];
#pragma unroll
    for (int isub = 0; isub < 2; isub++)
#pragma unroll
        for (int kc = 0; kc < 4; kc++)
            q[isub][kc] = *(const half8*)&Hq[(size_t)(iw + isub * 16 + lo16) * FOUT + kc * 32 + quad * 8];

    floatx4 O[8][2];
#pragma unroll
    for (int nt = 0; nt < 8; nt++)
#pragma unroll
        for (int s = 0; s < 2; s++) O[nt][s] = (floatx4){0.f, 0.f, 0.f, 0.f};
    float m_s[2] = {-1e12f, -1e12f}, l_s[2] = {0.f, 0.f};

    // per-lane mask row pointers: row i = iw + s*16 + lo16, window = j/64
    const unsigned long long* ar0 = adjb + (size_t)(iw + lo16) * (N / 64) + (jbeg >> 6);
    const unsigned long long* ar1 = ar0 + (size_t)16 * (N / 64);

    // prologue: stage KV tile 0 into buf 0 (global->LDS DMA)
    {
        const int jb0 = jbeg >> 6;
        const _Float16* gk = Kf + (size_t)jb0 * 8192;
        const _Float16* gv = Vf + (size_t)jb0 * 8192;
#pragma unroll
        for (int r = 0; r < 4; r++) {
            int goff = (r * 256 + tid) * 8;
            int loff = (r * 256 + wave * 64) * 8;           // wave-uniform base
            gload_lds16(gk + goff, &KV[0][loff]);
            gload_lds16(gv + goff, &KV[0][8192 + loff]);
        }
        __syncthreads();   // compiler drains vmcnt(0) before the barrier
    }

    int cur = 0;
    for (int it = 0; it < NIT; it++) {
        // ---- 1) issue next tile's global->LDS DMA first (in flight all iter)
        if (it + 1 < NIT) {
            const int jbn = (jbeg >> 6) + it + 1;
            const int nxt = cur ^ 1;
            const _Float16* gk = Kf + (size_t)jbn * 8192;
            const _Float16* gv = Vf + (size_t)jbn * 8192;
#pragma unroll
            for (int r = 0; r < 4; r++) {
                int goff = (r * 256 + tid) * 8;
                int loff = (r * 256 + wave * 64) * 8;
                gload_lds16(gk + goff, &KV[nxt][loff]);
                gload_lds16(gv + goff, &KV[nxt][8192 + loff]);
            }
        }

        unsigned long long mw[2] = { ar0[it], ar1[it] };

        const _Float16* kb = &KV[cur][0];
        const _Float16* vb = &KV[cur][8192];

        // ---- 2) S^T = K Q^T : j = c*32 + 8*quad + 4*ntj + r, i = s*16+lo16
        floatx4 S[2][2][2];   // [c][ntj][isub]
#pragma unroll
        for (int c = 0; c < 2; c++)
#pragma unroll
            for (int ntj = 0; ntj < 2; ntj++) {
                S[c][ntj][0] = (floatx4){0.f, 0.f, 0.f, 0.f};
                S[c][ntj][1] = (floatx4){0.f, 0.f, 0.f, 0.f};
#pragma unroll
                for (int kc = 0; kc < 4; kc++) {
                    half8 kf = *(const half8*)&kb[(((c * 2 + ntj) * 4 + kc) * 64 + lane) * 8];
                    S[c][ntj][0] = __builtin_amdgcn_mfma_f32_16x16x32_f16(kf, q[0][kc], S[c][ntj][0], 0, 0, 0);
                    S[c][ntj][1] = __builtin_amdgcn_mfma_f32_16x16x32_f16(kf, q[1][kc], S[c][ntj][1], 0, 0, 0);
                }
            }

        // ---- 3) online softmax (exp2 domain), in-place lrelu, deferred rescale
        half8 pb[2][2];       // [isub][c], element jj = 4*ntj + r
#pragma unroll
        for (int s = 0; s < 2; s++) {
            float mx = -1e12f;
#pragma unroll
            for (int c = 0; c < 2; c++)
#pragma unroll
                for (int ntj = 0; ntj < 2; ntj++)
#pragma unroll
                    for (int r = 0; r < 4; r++) {
                        float e = S[c][ntj][s][r];
                        e = fmaxf(e, 0.2f * e);          // lrelu (scale-commutes)
                        S[c][ntj][s][r] = e;             // store post-lrelu
                        mx = fmaxf(mx, e);
                    }
            mx = fmaxf(mx, __shfl_xor(mx, 16));
            mx = fmaxf(mx, __shfl_xor(mx, 32));
            // deferred rescale: only when max grew past ~4 nats (5.75 in log2)
            if (__any(mx > m_s[s] + 5.75f)) {
                float mn = fmaxf(m_s[s], mx);
                float al = exp2_fast(m_s[s] - mn);
                m_s[s] = mn;
                l_s[s] *= al;
#pragma unroll
                for (int nt = 0; nt < 8; nt++)
#pragma unroll
                    for (int r = 0; r < 4; r++)
                        O[nt][s][r] *= al;
            }

            unsigned long long mq = mw[s] >> (quad * 8);
            unsigned mh[2] = { (unsigned)mq, (unsigned)(mq >> 32) };
            float sum = 0.f;
#pragma unroll
            for (int c = 0; c < 2; c++)
#pragma unroll
                for (int ntj = 0; ntj < 2; ntj++)
#pragma unroll
                    for (int r = 0; r < 4; r++) {
                        float e = S[c][ntj][s][r] - m_s[s];
                        bool bit = (mh[c] >> (ntj * 4 + r)) & 1u;
                        float p = bit ? exp2_fast(e) : 0.f;
                        sum += p;
                        pb[s][c][ntj * 4 + r] = (_Float16)p;
                    }
            sum += __shfl_xor(sum, 16);
            sum += __shfl_xor(sum, 32);
            l_s[s] += sum;
        }

        // ---- 4) O^T += V^T P^T ----
#pragma unroll
        for (int c = 0; c < 2; c++)
#pragma unroll
            for (int nt = 0; nt < 8; nt++) {
                half8 vf = *(const half8*)&vb[((nt * 2 + c) * 64 + lane) * 8];
                O[nt][0] = __builtin_amdgcn_mfma_f32_16x16x32_f16(vf, pb[0][c], O[nt][0], 0, 0, 0);
                O[nt][1] = __builtin_amdgcn_mfma_f32_16x16x32_f16(vf, pb[1][c], O[nt][1], 0, 0, 0);
            }

        // ---- 5) single barrier: drains this wave's DMA (vmcnt 0) + syncs ----
        __syncthreads();
        cur ^= 1;
    }

    // epilogue: O^T[f][i] -> OpartT[js][f][i] (unnormalized) + (m,l)
#pragma unroll
    for (int nt = 0; nt < 8; nt++)
#pragma unroll
        for (int s = 0; s < 2; s++)
#pragma unroll
            for (int r = 0; r < 4; r++) {
                int f = nt * 16 + quad * 4 + r;
                int i = iw + s * 16 + lo16;
                OpartT[((size_t)js * FOUT + f) * N + i] = O[nt][s][r];
            }
    if (quad == 0) {
#pragma unroll
        for (int s = 0; s < 2; s++) {
            mpart[js * N + iw + s * 16 + lo16] = m_s[s];
            lpart[js * N + iw + s * 16 + lo16] = l_s[s];
        }
    }
}

// ---------------------------------------------------------------------------
// Combine: f-major partials -> normalize -> ELU -> out[i][f].
// m is in log2 domain -> exp2 for the cross-partial weights.
// ---------------------------------------------------------------------------
template<int JS>
__global__ __launch_bounds__(256)
void combine_kernel(const float* __restrict__ OpartT,
                    const float* __restrict__ mpart,
                    const float* __restrict__ lpart,
                    float* __restrict__ out)
{
    int idx = blockIdx.x * 256 + threadIdx.x;   // 128 f x 2048 i-groups
    int f  = idx >> 11;
    int i4 = (idx & 2047) << 2;

    float4 M = {-3e38f, -3e38f, -3e38f, -3e38f};
    float4 m[JS];
#pragma unroll
    for (int s = 0; s < JS; s++) {
        m[s] = *(const float4*)&mpart[s * N + i4];
        M.x = fmaxf(M.x, m[s].x); M.y = fmaxf(M.y, m[s].y);
        M.z = fmaxf(M.z, m[s].z); M.w = fmaxf(M.w, m[s].w);
    }
    float4 L = {0.f, 0.f, 0.f, 0.f};
    float4 w[JS];
#pragma unroll
    for (int s = 0; s < JS; s++) {
        float4 l = *(const float4*)&lpart[s * N + i4];
        w[s].x = exp2_fast(m[s].x - M.x); w[s].y = exp2_fast(m[s].y - M.y);
        w[s].z = exp2_fast(m[s].z - M.z); w[s].w = exp2_fast(m[s].w - M.w);
        L.x += l.x * w[s].x; L.y += l.y * w[s].y;
        L.z += l.z * w[s].z; L.w += l.w * w[s].w;
    }
    float4 o = {0.f, 0.f, 0.f, 0.f};
#pragma unroll
    for (int s = 0; s < JS; s++) {
        float4 v = *(const float4*)&OpartT[((size_t)s * FOUT + f) * N + i4];
        o.x += w[s].x * v.x; o.y += w[s].y * v.y;
        o.z += w[s].z * v.z; o.w += w[s].w * v.w;
    }
    float r0 = o.x / L.x, r1 = o.y / L.y, r2 = o.z / L.z, r3 = o.w / L.w;
    out[(size_t)(i4 + 0) * FOUT + f] = r0 > 0.f ? r0 : __expf(r0) - 1.f;
    out[(size_t)(i4 + 1) * FOUT + f] = r1 > 0.f ? r1 : __expf(r1) - 1.f;
    out[(size_t)(i4 + 2) * FOUT + f] = r2 > 0.f ? r2 : __expf(r2) - 1.f;
    out[(size_t)(i4 + 3) * FOUT + f] = r3 > 0.f ? r3 : __expf(r3) - 1.f;
}

// ---------------------------------------------------------------------------
extern "C" void kernel_launch(void* const* d_in, const int* in_sizes, int n_in,
                              void* d_out, int out_size, void* d_ws, size_t ws_size,
                              hipStream_t stream) {
    const float* inp = (const float*)d_in[0];
    const int*   adj = (const int*)d_in[1];
    const float* W0  = (const float*)d_in[2];
    const float* W1  = (const float*)d_in[3];
    const float* W2  = (const float*)d_in[4];
    float* out = (float*)d_out;

    constexpr int JS = 8;
    char* ws = (char*)d_ws;
    _Float16* H    = (_Float16*)(ws);                          // 2 MB
    _Float16* H2   = (_Float16*)(ws + (2u << 20));             // 2 MB
    _Float16* H3T  = (_Float16*)(ws + (4u << 20));             // 2 MB
    _Float16* Wf   = (_Float16*)(ws + (6u << 20));             // 192 KB
    _Float16* Kf   = (_Float16*)(ws + (7u << 20));             // 2 MB
    _Float16* Vf   = (_Float16*)(ws + (9u << 20));             // 2 MB
    float* OpartT  = (float*)(ws + (11u << 20));               // 32 MB
    float* mpart   = (float*)(ws + (43u << 20));               // 256 KB
    float* lpart   = (float*)(ws + (43u << 20) + (size_t)JS * N * sizeof(float));
    unsigned long long* adjb = (unsigned long long*)(ws + (44u << 20)); // 8 MB

    prep_kernel<<<2096, 256, 0, stream>>>(W0, W1, W2, Wf, adj, adjb);
    gemm3_kernel<<<dim3(N / 64, 2, 3), 256, 0, stream>>>(inp, Wf, H, H2, H3T);
    repackKV_kernel<<<1024, 256, 0, stream>>>(H2, H3T, Kf, Vf);
    attn_kernel<JS><<<(N / 128) * JS, 256, 0, stream>>>(H, Kf, Vf, adjb, OpartT, mpart, lpart);
    combine_kernel<JS><<<(FOUT * (N / 4)) / 256, 256, 0, stream>>>(OpartT, mpart, lpart, out);
}